// Round 8
// baseline (287.941 us; speedup 1.0000x reference)
//
#include <hip/hip_runtime.h>
#include <hip/hip_bf16.h>

typedef __attribute__((ext_vector_type(8))) short s16x8;
typedef __attribute__((ext_vector_type(16))) float f32x16;

#define MOD_SCALE 0.014731391274719739f  // 1/sqrt(512*9)

__device__ __forceinline__ void gload_lds16(const void* g, void* l) {
    __builtin_amdgcn_global_load_lds(
        (const __attribute__((address_space(1))) unsigned int*)g,
        (__attribute__((address_space(3))) unsigned int*)l, 16, 0, 0);
}

// Full drain + barrier (prologue only).
__device__ __forceinline__ void sync_drain() {
    __builtin_amdgcn_s_waitcnt(0);
    __syncthreads();
}

// Counted tap-end barriers (T4). lgkmcnt(0) retires this tap's ds_reads in
// every wave before the barrier, so DMA writes issued after the barrier
// cannot race readers (R5 race class). sched_barrier(0) fences the raw
// s_barrier (rule #18). vmcnt semantics (in-order retirement), per wave:
//   tap0-end: pending = W(prev-cb tap8)2 + X(cb+1)7|6 + W(2)2 = 11|10.
//     vmcnt(8) retires W(1)+[1 X] (wave0) / exactly W(1) (waves 1-3).
//   taps1-8-end: vmcnt(2) retires everything but the just-issued W(g+2)
//     (tap1-end also retires all X(cb+1), which has >=1 full tap of slack).
__device__ __forceinline__ void bar_vm8() {
    asm volatile("s_waitcnt vmcnt(8) lgkmcnt(0)" ::: "memory");
    __builtin_amdgcn_sched_barrier(0);
    __builtin_amdgcn_s_barrier();
    __builtin_amdgcn_sched_barrier(0);
}
__device__ __forceinline__ void bar_vm2() {
    asm volatile("s_waitcnt vmcnt(2) lgkmcnt(0)" ::: "memory");
    __builtin_amdgcn_sched_barrier(0);
    __builtin_amdgcn_s_barrier();
    __builtin_amdgcn_sched_barrier(0);
}

// ---------------------------------------------------------------------------
// xs layout (channel-blocked, proven): [b][cb=16][row=66][col=66][32ci*2B]
//   b stride 4,460,544 B; cb stride 278,784 B; entry stride 64 B.
//
// k_prep: MERGED back to one kernel (R13's split cost +6 us of launch gap;
// per-kernel observation is done). R12's proven body, grid 2568:
//   [0,512) xprep | [512,1032) border | [1032,2056) wprep | [2056,2568) demod
// ---------------------------------------------------------------------------
__global__ __launch_bounds__(256) void k_prep(const float* __restrict__ x,
                                              const float* __restrict__ style,
                                              const float* __restrict__ weight,
                                              __hip_bfloat16* __restrict__ xs,
                                              __hip_bfloat16* __restrict__ wb,
                                              float* __restrict__ dem) {
    __shared__ __align__(16) char sm[19456];  // xprep: 17408 tile + 2048 style
    const int t = threadIdx.x;
    const int bid = blockIdx.x;

    if (bid < 512) {
        // xprep: one block per (b,h); 4 iterations of 128 ci x 64 w
        const int b = bid >> 6, h = bid & 63;
        __hip_bfloat16 (*tile)[68] = (__hip_bfloat16(*)[68])sm;  // 17,408 B
        float* sf = (float*)(sm + 17408);                        // 512 floats
        sf[t] = style[b * 512 + t] * MOD_SCALE;
        sf[t + 256] = style[b * 512 + 256 + t] * MOD_SCALE;
        const float* xb = x + (size_t)b * 512 * 4096 + h * 64;
        const int cig = t & 3, w = t >> 2;
        char* ob = (char*)xs + (size_t)b * 4460544 +
                   (size_t)((h + 1) * 66 + 1) * 64;
        __syncthreads();
#pragma unroll
        for (int cq = 0; cq < 4; ++cq) {
#pragma unroll 4
            for (int it = 0; it < 8; ++it) {
                int idx = it * 256 + t;
                int cil = idx >> 4, w4 = idx & 15;
                int ci = cq * 128 + cil;
                float4 v = *(const float4*)(xb + (size_t)ci * 4096 + w4 * 4);
                float s = sf[ci];
                union { uint2 u2; __hip_bfloat16 q[4]; } pk;
                pk.q[0] = __float2bfloat16(v.x * s);
                pk.q[1] = __float2bfloat16(v.y * s);
                pk.q[2] = __float2bfloat16(v.z * s);
                pk.q[3] = __float2bfloat16(v.w * s);
                *(uint2*)&tile[cil][w4 * 4] = pk.u2;  // 136B row: 8-aligned
            }
            __syncthreads();
#pragma unroll
            for (int cbl = 0; cbl < 4; ++cbl) {
                const int cb = cq * 4 + cbl;
                union { uint4 u; __hip_bfloat16 q[8]; } pk;
#pragma unroll
                for (int j = 0; j < 8; ++j)
                    pk.q[j] = tile[cbl * 32 + cig * 8 + j][w];
                *(uint4*)(ob + (size_t)cb * 278784 + w * 64 + cig * 16) = pk.u;
            }
            __syncthreads();
        }
    } else if (bid < 1032) {
        const int idx = (bid - 512) * 256 + t;
        const int b = idx / 16640;
        const int r2 = idx - b * 16640;
        const int cb = r2 / 1040;
        const int r3 = r2 - cb * 1040;
        const int pair = r3 >> 2;
        const int chunk = r3 & 3;
        int pr, pc;
        if (pair < 66)       { pr = 0;          pc = pair; }
        else if (pair < 132) { pr = 65;         pc = pair - 66; }
        else if (pair < 196) { pr = pair - 131; pc = 0; }
        else                 { pr = pair - 195; pc = 65; }
        char* d = (char*)xs +
                  ((size_t)(b * 16 + cb) * 4356 + pr * 66 + pc) * 64 +
                  chunk * 16;
        *(uint4*)d = make_uint4(0u, 0u, 0u, 0u);
    } else if (bid < 2056) {
        const int r = bid - 1032;
        float* lds = (float*)sm;
        const int p0 = r * 256;
        const float* src = weight + (size_t)p0 * 9;
#pragma unroll
        for (int k = 0; k < 9; ++k) lds[k * 256 + t] = src[k * 256 + t];
        __syncthreads();
#pragma unroll
        for (int tap = 0; tap < 9; ++tap)
            wb[(size_t)tap * 262144 + p0 + t] = __float2bfloat16(lds[t * 9 + tap]);
    } else {
        const int co = bid - 2056;
        float* s2 = (float*)sm;
        for (int i = t; i < 4096; i += 256) { float v = style[i]; s2[i] = v * v; }
        __syncthreads();
        const float4* wp = (const float4*)(weight + (size_t)co * 4608);
        float acc[8] = {0.f, 0.f, 0.f, 0.f, 0.f, 0.f, 0.f, 0.f};
        for (int j = t; j < 1152; j += 256) {
            float4 v = wp[j];
            float w2[4] = {v.x * v.x, v.y * v.y, v.z * v.z, v.w * v.w};
            int base = j * 4;
#pragma unroll
            for (int e = 0; e < 4; ++e) {
                int ci = (base + e) / 9;
                float ww = w2[e];
#pragma unroll
                for (int bb = 0; bb < 8; ++bb) acc[bb] += ww * s2[bb * 512 + ci];
            }
        }
#pragma unroll
        for (int bb = 0; bb < 8; ++bb)
            for (int off = 32; off > 0; off >>= 1)
                acc[bb] += __shfl_down(acc[bb], off);
        float* red = (float*)(sm + 16384);
        const int wv = t >> 6, lane = t & 63;
        if (lane == 0) {
#pragma unroll
            for (int bb = 0; bb < 8; ++bb) red[wv * 8 + bb] = acc[bb];
        }
        __syncthreads();
        if (t < 8) {
            float s = red[t] + red[8 + t] + red[16 + t] + red[24 + t];
            const float S2 = MOD_SCALE * MOD_SCALE;
            dem[t * 512 + co] = rsqrtf(S2 * s + 1e-8f);
        }
    }
}

// ---------------------------------------------------------------------------
// Conv: implicit GEMM, 32x32x16 MFMA. Block 128co x 256sp, 4 waves,
// wave tile 64co x 128sp (2x4 frags). R14 schedule:
//   - X DOUBLE buffer (2 x 25,344 B): X(cb+1) issued at cb top into the
//     buffer last read in cb-1 (its readers retired at cb-1 tap8's
//     lgkmcnt(0) barrier). This removes the per-cb serial restage drain
//     (issue + vmcnt(0) with ZERO slack) that every prior variant carried.
//   - W TRIPLE buffer (3 x 8,192 B), per-tap rotation: tap computes from
//     Wl[tap%3] (9 % 3 == 0 -> compile-time), tap issues W(tap+2) into
//     Wl[(tap+2)%3]. Counted vmcnt per tap end: vmcnt(8) at tap0 (retires
//     W(1), tolerates wave0's 7th X load), vmcnt(2) at taps 1-8 (T4:
//     W(g+2) stays in flight across the barrier; tap1-end also retires X).
//   - Every barrier: lgkmcnt(0) before s_barrier -> no DMA/reader races.
// Rotation swizzle unchanged. LDS 75,264 B -> exactly 2 blocks/CU. Grid 512.
// ---------------------------------------------------------------------------
__global__ __launch_bounds__(256, 2) void k_conv(
    const __hip_bfloat16* __restrict__ xs,   // [b][16][66][66][64B] blocked
    const __hip_bfloat16* __restrict__ wb,   // [9][512][512] tap-major
    const float* __restrict__ demod,
    const float* __restrict__ noise,
    const float* __restrict__ bias,
    const float* __restrict__ nstr,
    float* __restrict__ out) {
    __shared__ __align__(16) char Xl[2][25344];  // 396 entries x 64 B, dbuf
    __shared__ __align__(16) char Wl[3][8192];   // per-tap rotation

    const int t = threadIdx.x;
    const int bi = blockIdx.x;
    const int spat = bi & 127;            // same spat -> same bi%8 -> same XCD
    const int b = spat >> 4;
    const int h0 = (spat & 15) << 2;
    const int co0 = (bi >> 7) << 7;
    const int lane = t & 63;
    const int wv = t >> 6;
    const int wm = wv & 1, wn = wv >> 1;
    const int el = lane & 31;
    const int hk = lane >> 5;

    f32x16 acc[2][4];
#pragma unroll
    for (int i = 0; i < 2; ++i)
#pragma unroll
        for (int j = 0; j < 4; ++j)
#pragma unroll
            for (int k = 0; k < 16; ++k) acc[i][j][k] = 0.f;

    // ---- staging source pointers (rotation-swizzled) ----
    const char* xsb = (const char*)xs + (size_t)b * 4460544;
    const char* xsrc[7];
#pragma unroll
    for (int i = 0; i < 6; ++i) {
        int g = i * 256 + t;
        int e = g >> 2, s = g & 3;
        int gc = (s - (e >> 2)) & 3;
        int row = e / 66, col = e - row * 66;
        xsrc[i] = xsb + (size_t)((h0 + row) * 66 + col) * 64 + gc * 16;
    }
    {   // tail entries 384..395 (threads 0..47 only)
        int g = 1536 + t;
        int e = g >> 2, s = g & 3;
        int gc = (s - (e >> 2)) & 3;
        int row = e / 66, col = e - row * 66;
        xsrc[6] = xsb + (size_t)((h0 + row) * 66 + col) * 64 + gc * 16;
    }
    const char* wsrc[2];
#pragma unroll
    for (int i = 0; i < 2; ++i) {
        int g = i * 256 + t;
        int e = g >> 2, s = g & 3;
        int gc = (s - (e >> 2)) & 3;
        wsrc[i] = (const char*)wb + (size_t)(co0 + e) * 1024 + gc * 16;
    }
    const int wvoff = wv << 10;

    // ---- prologue: X(0) -> Xl[0]; W(0) -> Wl[0], W(1) -> Wl[1]; drain ----
#pragma unroll
    for (int i = 0; i < 6; ++i) gload_lds16(xsrc[i], Xl[0] + i * 4096 + wvoff);
    if (t < 48) gload_lds16(xsrc[6], Xl[0] + 24576);
#pragma unroll
    for (int tt = 0; tt < 2; ++tt)
#pragma unroll
        for (int i = 0; i < 2; ++i)
            gload_lds16(wsrc[i] + (size_t)tt * 524288,
                        Wl[tt] + i * 4096 + wvoff);
    sync_drain();

    for (int cb = 0; cb < 16; ++cb) {
        const char* Xr = Xl[cb & 1];
        char* Xw = Xl[(cb + 1) & 1];
        // ---- issue X(cb+1) at cb top (9 taps of slack; cb15: dead reload) ----
        const size_t xo = (size_t)(cb < 15 ? cb + 1 : cb) * 278784;
#pragma unroll
        for (int i = 0; i < 6; ++i)
            gload_lds16(xsrc[i] + xo, Xw + i * 4096 + wvoff);
        if (t < 48) gload_lds16(xsrc[6] + xo, Xw + 24576);

        const int cboff = cb * 64;
        const int ncboff = (cb < 15) ? cboff + 64 : cboff;  // cb15: dead dummy
#pragma unroll
        for (int tap = 0; tap < 9; ++tap) {
            // ---- issue W(tap+2) into Wl[(tap+2)%3] ----
            {
                const size_t soff =
                    (tap < 7) ? (size_t)(tap + 2) * 524288 + cboff
                              : (tap == 7 ? (size_t)ncboff
                                          : (size_t)524288 + ncboff);
                char* dst = Wl[(tap + 2) % 3] + wvoff;
#pragma unroll
                for (int i = 0; i < 2; ++i)
                    gload_lds16(wsrc[i] + soff, dst + i * 4096);
            }
            // ---- compute tap from Wl[tap%3] + Xr (dh = tap/3, dw = tap%3) ----
            const int dh = tap / 3, dw = tap % 3;
            const char* Wb = Wl[tap % 3];
#pragma unroll
            for (int ks = 0; ks < 2; ++ks) {
                const int c = 2 * ks + hk;
                s16x8 af[2], bfr[4];
#pragma unroll
                for (int mi = 0; mi < 2; ++mi) {
                    int e = wm * 64 + mi * 32 + el;
                    af[mi] = *(const s16x8*)(Wb + e * 64 +
                                             (((c + (e >> 2)) & 3) << 4));
                }
#pragma unroll
                for (int ni = 0; ni < 4; ++ni) {
                    int e = (2 * wn + (ni >> 1) + dh) * 66 + dw +
                            (ni & 1) * 32 + el;
                    bfr[ni] = *(const s16x8*)(Xr + e * 64 +
                                              (((c + (e >> 2)) & 3) << 4));
                }
#pragma unroll
                for (int mi = 0; mi < 2; ++mi)
#pragma unroll
                    for (int ni = 0; ni < 4; ++ni)
                        acc[mi][ni] = __builtin_amdgcn_mfma_f32_32x32x16_bf16(
                            af[mi], bfr[ni], acc[mi][ni], 0, 0, 0);
            }
            // ---- counted tap-end barrier ----
            if (tap == 0) bar_vm8();
            else          bar_vm2();
        }
    }

    // ---- epilogue: *demod + noise*strength + bias, leaky_relu(0.2)*sqrt(2) ----
    const float nsv = nstr[0];
    const float LR = 1.4142135623730951f;
#pragma unroll
    for (int mi = 0; mi < 2; ++mi) {
        float dm[16], bs[16];
#pragma unroll
        for (int rg = 0; rg < 16; ++rg) {
            int co = co0 + wm * 64 + mi * 32 + (rg & 3) + 8 * (rg >> 2) + 4 * hk;
            dm[rg] = demod[b * 512 + co];
            bs[rg] = bias[co];
        }
#pragma unroll
        for (int ni = 0; ni < 4; ++ni) {
            int h = h0 + 2 * wn + (ni >> 1);
            int w = (ni & 1) * 32 + el;
            float nz = nsv * noise[h * 64 + w];
#pragma unroll
            for (int rg = 0; rg < 16; ++rg) {
                int co = co0 + wm * 64 + mi * 32 + (rg & 3) + 8 * (rg >> 2) +
                         4 * hk;
                float v = acc[mi][ni][rg] * dm[rg] + nz + bs[rg];
                v = (v >= 0.f ? v : 0.2f * v) * LR;
                out[(((size_t)b * 512 + co) * 64 + h) * 64 + w] = v;
            }
        }
    }
}

// ---------------------------------------------------------------------------
extern "C" void kernel_launch(void* const* d_in, const int* in_sizes, int n_in,
                              void* d_out, int out_size, void* d_ws, size_t ws_size,
                              hipStream_t stream) {
    const float* x      = (const float*)d_in[0];
    const float* style  = (const float*)d_in[1];
    const float* noise  = (const float*)d_in[2];
    const float* weight = (const float*)d_in[3];
    const float* bias   = (const float*)d_in[4];
    const float* nstr   = (const float*)d_in[5];
    float* out = (float*)d_out;

    char* ws = (char*)d_ws;
    __hip_bfloat16* xs = (__hip_bfloat16*)ws;              // 35,684,352 B (blocked)
    __hip_bfloat16* wb = (__hip_bfloat16*)(ws + 35684352); //  4,718,592 B
    float* demod = (float*)(ws + 35684352 + 4718592);      //     16,384 B

    k_prep<<<2568, 256, 0, stream>>>(x, style, weight, xs, wb, demod);
    k_conv<<<512, 256, 0, stream>>>(xs, wb, demod, noise, bias, nstr, out);
}